// Round 8
// baseline (308.687 us; speedup 1.0000x reference)
//
#include <hip/hip_runtime.h>
#include <hip/hip_bf16.h>

// ForcedDAGPlanner: B=16,S=4096,E=1024,M=64,N=32,H=8,D=128
//   scores[b,h,s] = x[b,s,:]·qk[h,:] + qb[h]   (qk = (q·Wk)/sqrt(D), 8x1024)
//   xa[b,h,:]     = softmax-weighted sum of x rows (unnormalized partials + l)
//   ctx[b,j]      = xa[b,h(j),:]·wv[j,:] + bv[j]
//   k_nodes = 32 -> node_mask all-true.
// R8: tail collapsed into ONE persistent kernel (128 blocks, all co-resident)
// with device-scope atomic grid barriers. 4 launches total. nm phase coalesced
// via paired half-wave dots.

#define DEVFN __device__ __forceinline__

constexpr float SCALE = 0.08838834764831845f; // 1/sqrt(128)

// workspace offsets (floats)
constexpr size_t OFF_QVEC  = 0;        // 1024
constexpr size_t OFF_QKT   = 1024;     // 8192  [h*1024+e]
constexpr size_t OFF_QB    = 9216;     // 8
constexpr size_t OFF_LPART = 9224;     // 4096  [cid*8+h]
constexpr size_t OFF_CTX   = 13320;    // 16384
constexpr size_t OFF_TREP  = 29704;    // 16384
constexpr size_t OFF_TM    = 46088;    // 1024
constexpr size_t OFF_NMG   = 47112;    // 32768
constexpr size_t OFF_PART  = 79880;    // 512*8*1024 = 4194304 [cid][h][e]
constexpr size_t OFF_BAR   = 4274184;  // 4 ints (16 B) barrier state
// total ~17.1 MB of d_ws

// output offsets (f32 elements)
constexpr size_t OUT_EMB  = 0;        // 16*32*1024
constexpr size_t OUT_ADJ  = 524288;   // 16*32*32
constexpr size_t OUT_SURF = 540672;   // 16
constexpr size_t OUT_CPLX = 540688;   // 16*32
constexpr size_t OUT_MASK = 541200;   // 16*32

constexpr int TAIL_BLOCKS = 128;

DEVFN float gelu_exact(float x) {
  return 0.5f * x * (1.0f + erff(x * 0.70710678118654752f));
}
DEVFN float softplus_f(float x) {
  return fmaxf(x, 0.0f) + log1pf(expf(-fabsf(x)));
}
DEVFN float dot4(float4 a, float4 b) {
  return a.x * b.x + a.y * b.y + a.z * b.z + a.w * b.w;
}

// device-scope generation barrier; all TAIL_BLOCKS blocks must be co-resident.
DEVFN void grid_sync(int* counter, unsigned int* gen) {
  __threadfence();  // release this thread's global writes (device scope)
  __syncthreads();
  if (threadIdx.x == 0) {
    unsigned int g = __hip_atomic_load(gen, __ATOMIC_ACQUIRE,
                                       __HIP_MEMORY_SCOPE_AGENT);
    int arrived = __hip_atomic_fetch_add(counter, 1, __ATOMIC_ACQ_REL,
                                         __HIP_MEMORY_SCOPE_AGENT) + 1;
    if (arrived == TAIL_BLOCKS) {
      __hip_atomic_store(counter, 0, __ATOMIC_RELAXED,
                         __HIP_MEMORY_SCOPE_AGENT);
      __hip_atomic_fetch_add(gen, 1u, __ATOMIC_ACQ_REL,
                             __HIP_MEMORY_SCOPE_AGENT);
    } else {
      while (__hip_atomic_load(gen, __ATOMIC_ACQUIRE,
                               __HIP_MEMORY_SCOPE_AGENT) == g)
        __builtin_amdgcn_s_sleep(2);
    }
  }
  __syncthreads();
  __threadfence();  // acquire side
}

// ---- K0: qvec[i] = task_query · wq[i,:] + bq[i]   (wave per output)
__global__ void k_qvec(const float* __restrict__ tq, const float* __restrict__ wq,
                       const float* __restrict__ bq, float* __restrict__ qvec) {
  int wid = threadIdx.x >> 6, lane = threadIdx.x & 63;
  int i = blockIdx.x * 4 + wid;  // 256 blocks -> 1024 outputs
  const float* wrow = wq + (size_t)i * 1024;
  float acc = 0.f;
#pragma unroll
  for (int k = 0; k < 4; ++k) {
    int e = lane * 4 + k * 256;
    acc += dot4(*(const float4*)(tq + e), *(const float4*)(wrow + e));
  }
#pragma unroll
  for (int off = 32; off; off >>= 1) acc += __shfl_xor(acc, off);
  if (lane == 0) qvec[i] = acc + bq[i];
}

// ---- K0b: qkT[h*1024+e] = SCALE * sum_d qvec[h*128+d]*wk[(h*128+d)*1024+e]; qb[h]
__global__ void k_qk(const float* __restrict__ qvec, const float* __restrict__ wk,
                     const float* __restrict__ bk, float* __restrict__ qkT,
                     float* __restrict__ qb) {
  __shared__ float qh[128];
  int h = blockIdx.x >> 2, e0 = (blockIdx.x & 3) * 256;  // 32 blocks
  int t = threadIdx.x;
  if (t < 128) qh[t] = qvec[h * 128 + t];
  __syncthreads();
  int e = e0 + t;
  float acc = 0.f;
#pragma unroll 32
  for (int d = 0; d < 128; ++d)
    acc += qh[d] * wk[(size_t)(h * 128 + d) * 1024 + e];
  qkT[h * 1024 + e] = acc * SCALE;
  if (t == 0 && e0 == 0) {
    float s = 0.f;
    for (int d = 0; d < 128; ++d) s += qh[d] * bk[h * 128 + d];
    qb[h] = s * SCALE;
  }
}

// ---- K1 v4 (unchanged): fused score+exp+weighted-sum, single x pass.
__global__ __launch_bounds__(256, 2) void k_fused(
    const float* __restrict__ x, const float* __restrict__ qkT,
    const float* __restrict__ qb, float* __restrict__ partial,
    float* __restrict__ lpart) {
  __shared__ __align__(16) float lds[8 * 1024];
  __shared__ float s_ll[8];
  int t = threadIdx.x, wid = t >> 6, lane = t & 63;
  int rh = wid >> 1, hg = wid & 1;

  float4 qr[4][4];
#pragma unroll
  for (int hh = 0; hh < 4; ++hh)
#pragma unroll
    for (int k = 0; k < 4; ++k)
      qr[hh][k] = *(const float4*)(qkT + (hg * 4 + hh) * 1024 + k * 256 + lane * 4);
  float qbr[4];
#pragma unroll
  for (int hh = 0; hh < 4; ++hh) qbr[hh] = qb[hg * 4 + hh];

  float4 acc[4][4];
#pragma unroll
  for (int hh = 0; hh < 4; ++hh)
#pragma unroll
    for (int k = 0; k < 4; ++k) acc[hh][k] = make_float4(0.f, 0.f, 0.f, 0.f);
  float lsum[4] = {0.f, 0.f, 0.f, 0.f};

  int row0 = blockIdx.x * 128 + rh * 64;
  const float* xr = x + ((size_t)row0 << 10) + lane * 4;
  float4 A0 = *(const float4*)(xr + 0);
  float4 A1 = *(const float4*)(xr + 256);
  float4 A2 = *(const float4*)(xr + 512);
  float4 A3 = *(const float4*)(xr + 768);
  float4 B0 = *(const float4*)(xr + 1024);
  float4 B1 = *(const float4*)(xr + 1280);
  float4 B2 = *(const float4*)(xr + 1536);
  float4 B3 = *(const float4*)(xr + 1792);

  for (int r = 0; r < 64; ++r) {
    float4 c0 = A0, c1 = A1, c2 = A2, c3 = A3;
    A0 = B0; A1 = B1; A2 = B2; A3 = B3;
    if (r < 62) {
      const float* nx = xr + ((size_t)(r + 2) << 10);
      B0 = *(const float4*)(nx + 0);
      B1 = *(const float4*)(nx + 256);
      B2 = *(const float4*)(nx + 512);
      B3 = *(const float4*)(nx + 768);
    }
    float s[4];
#pragma unroll
    for (int hh = 0; hh < 4; ++hh)
      s[hh] = dot4(c0, qr[hh][0]) + dot4(c1, qr[hh][1]) +
              dot4(c2, qr[hh][2]) + dot4(c3, qr[hh][3]);
#pragma unroll
    for (int off = 1; off <= 32; off <<= 1)
#pragma unroll
      for (int hh = 0; hh < 4; ++hh) s[hh] += __shfl_xor(s[hh], off);
    float w[4];
#pragma unroll
    for (int hh = 0; hh < 4; ++hh) {
      w[hh] = expf(s[hh] + qbr[hh]);
      lsum[hh] += w[hh];
    }
#pragma unroll
    for (int hh = 0; hh < 4; ++hh) {
      acc[hh][0].x += w[hh] * c0.x; acc[hh][0].y += w[hh] * c0.y;
      acc[hh][0].z += w[hh] * c0.z; acc[hh][0].w += w[hh] * c0.w;
      acc[hh][1].x += w[hh] * c1.x; acc[hh][1].y += w[hh] * c1.y;
      acc[hh][1].z += w[hh] * c1.z; acc[hh][1].w += w[hh] * c1.w;
      acc[hh][2].x += w[hh] * c2.x; acc[hh][2].y += w[hh] * c2.y;
      acc[hh][2].z += w[hh] * c2.z; acc[hh][2].w += w[hh] * c2.w;
      acc[hh][3].x += w[hh] * c3.x; acc[hh][3].y += w[hh] * c3.y;
      acc[hh][3].w += w[hh] * c3.w; acc[hh][3].z += w[hh] * c3.z;
    }
  }
  if (rh == 1) {
#pragma unroll
    for (int hh = 0; hh < 4; ++hh)
#pragma unroll
      for (int k = 0; k < 4; ++k)
        *(float4*)(lds + (hg * 4 + hh) * 1024 + k * 256 + lane * 4) = acc[hh][k];
    if (lane == 0)
#pragma unroll
      for (int hh = 0; hh < 4; ++hh) s_ll[hg * 4 + hh] = lsum[hh];
  }
  __syncthreads();
  if (rh == 0) {
    size_t base = (((size_t)blockIdx.x * 8 + hg * 4) << 10) + lane * 4;
#pragma unroll
    for (int hh = 0; hh < 4; ++hh)
#pragma unroll
      for (int k = 0; k < 4; ++k) {
        const float4 o = *(const float4*)(lds + (hg * 4 + hh) * 1024 + k * 256 + lane * 4);
        float4 v = acc[hh][k];
        v.x += o.x; v.y += o.y; v.z += o.z; v.w += o.w;
        *(float4*)(partial + base + ((size_t)hh << 10) + k * 256) = v;
      }
    if (lane == 0)
#pragma unroll
      for (int hh = 0; hh < 4; ++hh)
        lpart[blockIdx.x * 8 + hg * 4 + hh] = lsum[hh] + s_ll[hg * 4 + hh];
  }
}

// ---- K2: persistent tail. 128 blocks x 256 threads, 5 phases, 4 grid syncs.
__global__ __launch_bounds__(256) void k_tailp(
    const float* __restrict__ partial, const float* __restrict__ lpart,
    const float* __restrict__ wv, const float* __restrict__ bv,
    const float* __restrict__ wo, const float* __restrict__ bo,
    const float* __restrict__ mp_w, const float* __restrict__ mp_b,
    const float* __restrict__ ln_w, const float* __restrict__ ln_b,
    const float* __restrict__ ng_w1, const float* __restrict__ ng_b1,
    const float* __restrict__ ng_w2, const float* __restrict__ ng_b2,
    const float* __restrict__ ep_w, const float* __restrict__ ep_b,
    const float* __restrict__ cp_w1, const float* __restrict__ cp_b1,
    const float* __restrict__ cp_w2, const float* __restrict__ cp_b2,
    const float* __restrict__ np_w, const float* __restrict__ np_b,
    float* __restrict__ ctx, float* __restrict__ trep,
    float* __restrict__ tmg, float* __restrict__ nmg,
    int* __restrict__ bar_counter, unsigned int* __restrict__ bar_gen,
    float* __restrict__ out) {
  __shared__ __align__(16) float smem[5184];
  __shared__ float s_misc;
  int blk = blockIdx.x, t = threadIdx.x, wid = t >> 6, lane = t & 63;

  // ---- P1: combctx. block = (b,h): reduce xa slice, then 128 ctx dots.
  {
    int b = blk >> 3, h = blk & 7;
    float4 s4 = make_float4(0.f, 0.f, 0.f, 0.f);
#pragma unroll 8
    for (int c = 0; c < 32; ++c) {
      float4 v = *(const float4*)(partial +
          (((size_t)(b * 32 + c) * 8 + h) << 10) + t * 4);
      s4.x += v.x; s4.y += v.y; s4.z += v.z; s4.w += v.w;
    }
    *(float4*)(smem + t * 4) = s4;
    if (t == 0) {
      float s = 0.f;
#pragma unroll
      for (int c = 0; c < 32; ++c) s += lpart[(b * 32 + c) * 8 + h];
      s_misc = 1.0f / s;
    }
    __syncthreads();
    float linv = s_misc;
    for (int it = 0; it < 32; ++it) {
      int j = h * 128 + wid * 32 + it;
      const float* wr = wv + (size_t)j * 1024 + lane * 4;
      const float* xr = smem + lane * 4;
      float acc = 0.f;
#pragma unroll
      for (int k = 0; k < 4; ++k)
        acc += dot4(*(const float4*)(xr + k * 256), *(const float4*)(wr + k * 256));
#pragma unroll
      for (int off = 32; off; off >>= 1) acc += __shfl_xor(acc, off);
      if (lane == 0) ctx[b * 1024 + j] = acc * linv + bv[j];
    }
  }
  grid_sync(bar_counter, bar_gen);

  // ---- P2: trep. block = (b, i-chunk of 128).
  {
    int b = blk >> 3, ch = blk & 7;
    *(float4*)(smem + t * 4) = *(const float4*)(ctx + b * 1024 + t * 4);
    __syncthreads();
    for (int it = 0; it < 32; ++it) {
      int i = ch * 128 + wid * 32 + it;
      const float* wr = wo + (size_t)i * 1024 + lane * 4;
      const float* xr = smem + lane * 4;
      float acc = 0.f;
#pragma unroll
      for (int k = 0; k < 4; ++k)
        acc += dot4(*(const float4*)(xr + k * 256), *(const float4*)(wr + k * 256));
#pragma unroll
      for (int off = 32; off; off >>= 1) acc += __shfl_xor(acc, off);
      if (lane == 0) trep[b * 1024 + i] = acc + bo[i];
    }
  }
  grid_sync(bar_counter, bar_gen);

  // ---- P3: tm. block = (b, m-chunk of 8): 2 dots per wave.
  {
    int b = blk >> 3, mg = blk & 7;
    *(float4*)(smem + t * 4) = *(const float4*)(trep + b * 1024 + t * 4);
    __syncthreads();
#pragma unroll
    for (int it = 0; it < 2; ++it) {
      int m = mg * 8 + wid * 2 + it;
      const float* wr = mp_w + (size_t)m * 1024 + lane * 4;
      const float* xr = smem + lane * 4;
      float acc = 0.f;
#pragma unroll
      for (int k = 0; k < 4; ++k)
        acc += dot4(*(const float4*)(xr + k * 256), *(const float4*)(wr + k * 256));
#pragma unroll
      for (int off = 32; off; off >>= 1) acc += __shfl_xor(acc, off);
      if (lane == 0) tmg[b * 64 + m] = acc + mp_b[m];
    }
  }
  grid_sync(bar_counter, bar_gen);

  // ---- P4: nm. block = (b, nodegroup of 4 nodes). LN(tm)+h2 redundant/block.
  {
    int b = blk >> 3, ng = blk & 7;
    float* s_tm = smem;          // 64
    float* s_h2 = smem + 128;    // 128
    float* s_np = smem + 256;    // 256
    if (wid == 0) {
      float v = tmg[b * 64 + lane];
      float sm = v;
#pragma unroll
      for (int off = 32; off; off >>= 1) sm += __shfl_xor(sm, off);
      float mu = sm * (1.f / 64.f);
      float d = v - mu;
      float vv = d * d;
#pragma unroll
      for (int off = 32; off; off >>= 1) vv += __shfl_xor(vv, off);
      float rstd = 1.f / sqrtf(vv * (1.f / 64.f) + 1e-5f);
      s_tm[lane] = d * rstd * ln_w[lane] + ln_b[lane];
    }
    __syncthreads();
    if (t < 128) {
      float acc = ng_b1[t];
      const float* wr = ng_w1 + (size_t)t * 64;
#pragma unroll 16
      for (int m = 0; m < 64; ++m) acc += s_tm[m] * wr[m];
      s_h2[t] = gelu_exact(acc);
    }
    __syncthreads();
    // 256 dots of length 128: paired half-wave (lanes 0-31 out A, 32-63 out B)
    int half = lane >> 5, hl = lane & 31;
    float4 hv4 = *(const float4*)(s_h2 + hl * 4);
    for (int it = 0; it < 32; ++it) {
      int ol = wid * 64 + it * 2 + half;      // 0..255
      int o = ng * 256 + ol;                   // row of ng_w2 (0..2047)
      float4 wv4 = *(const float4*)(ng_w2 + (size_t)o * 128 + hl * 4);
      float a = dot4(wv4, hv4);
#pragma unroll
      for (int off = 1; off <= 16; off <<= 1) a += __shfl_xor(a, off);
      if (hl == 0) s_np[ol] = a + ng_b2[o];
    }
    __syncthreads();
    {  // LN per node; wave w handles node ng*4+w
      float v = s_np[wid * 64 + lane];
      float sm = v;
#pragma unroll
      for (int off = 32; off; off >>= 1) sm += __shfl_xor(sm, off);
      float mu = sm * (1.f / 64.f);
      float d = v - mu;
      float vv = d * d;
#pragma unroll
      for (int off = 32; off; off >>= 1) vv += __shfl_xor(vv, off);
      float rstd = 1.f / sqrtf(vv * (1.f / 64.f) + 1e-5f);
      nmg[b * 2048 + (ng * 4 + wid) * 64 + lane] =
          d * rstd * ln_w[lane] + ln_b[lane];
    }
  }
  grid_sync(bar_counter, bar_gen);

  // ---- P5: heads (blocks 0..15) + node embeddings (blocks 16..79)
  if (blk >= 80) return;
  float* s_nm = smem;          // 2048
  float* s_t  = smem + 2048;   // 2048
  float* s_c1 = smem + 4096;   // 1024
  float* s_cx = smem + 5120;   // 32
  if (blk < 16) {
    int b = blk;
    for (int i = t; i < 512; i += 256)
      ((float4*)s_nm)[i] = ((const float4*)(nmg + (size_t)b * 2048))[i];
    __syncthreads();
    for (int o = t; o < 1024; o += 256) {
      int i = o >> 5, r = o & 31;
      float acc = cp_b1[r];
      const float* wr = cp_w1 + (size_t)r * 64;
#pragma unroll 8
      for (int m = 0; m < 64; ++m) acc += s_nm[i * 64 + m] * wr[m];
      s_c1[o] = gelu_exact(acc);
    }
    __syncthreads();
    if (t < 32) {
      float acc = cp_b2[0];
#pragma unroll 8
      for (int r = 0; r < 32; ++r) acc += s_c1[t * 32 + r] * cp_w2[r];
      float sp = softplus_f(acc);
      s_cx[t] = sp;
      out[OUT_CPLX + b * 32 + t] = sp;
      out[OUT_MASK + b * 32 + t] = 1.0f;
    }
    __syncthreads();
    if (wid == 0) {
      float v = (lane < 32) ? s_cx[lane] : 0.f;
#pragma unroll
      for (int off = 32; off; off >>= 1) v += __shfl_xor(v, off);
      if (lane == 0) out[OUT_SURF + b] = v;
    }
    for (int o = t; o < 2048; o += 256) {
      int i = o >> 6, n = o & 63;
      float acc = 0.f;
#pragma unroll 8
      for (int m = 0; m < 64; ++m) acc += s_nm[i * 64 + m] * ep_w[m * 64 + n];
      s_t[o] = acc;
    }
    __syncthreads();
    for (int o = t; o < 1024; o += 256) {
      int i = o >> 5, j = o & 31;
      float acc = ep_b[0];
#pragma unroll 8
      for (int n = 0; n < 64; ++n) acc += s_t[i * 64 + n] * s_nm[j * 64 + n];
      float sg = 1.f / (1.f + expf(-acc));
      float val = (j > i && sg > 0.3f) ? 1.f : 0.f;
      out[OUT_ADJ + (size_t)b * 1024 + i * 32 + j] = val;
    }
  } else {
    int idx = blk - 16;  // 64 blocks
    int b = idx >> 2, e0 = (idx & 3) * 256;
    *(float4*)(s_nm + t * 4) = *(const float4*)(nmg + b * 2048 + t * 4);
    *(float4*)(s_nm + 1024 + t * 4) =
        *(const float4*)(nmg + b * 2048 + 1024 + t * 4);
    __syncthreads();
    int e = e0 + t;
    float4 w[16];
    const float* wr = np_w + (size_t)e * 64;
#pragma unroll
    for (int k = 0; k < 16; ++k) w[k] = *(const float4*)(wr + k * 4);
    float bias = np_b[e];
    for (int i = 0; i < 32; ++i) {
      float acc = bias;
#pragma unroll
      for (int k = 0; k < 16; ++k)
        acc += dot4(w[k], *(const float4*)(s_nm + i * 64 + k * 4));
      out[OUT_EMB + (size_t)(b * 32 + i) * 1024 + e] = acc;
    }
  }
}

extern "C" void kernel_launch(void* const* d_in, const int* in_sizes, int n_in,
                              void* d_out, int out_size, void* d_ws, size_t ws_size,
                              hipStream_t stream) {
  (void)in_sizes; (void)n_in; (void)out_size; (void)ws_size;
  const float* x    = (const float*)d_in[0];
  const float* tq   = (const float*)d_in[1];
  const float* wq   = (const float*)d_in[2];
  const float* bq   = (const float*)d_in[3];
  const float* wk   = (const float*)d_in[4];
  const float* bk   = (const float*)d_in[5];
  const float* wv   = (const float*)d_in[6];
  const float* bv   = (const float*)d_in[7];
  const float* wo   = (const float*)d_in[8];
  const float* bo   = (const float*)d_in[9];
  const float* mp_w = (const float*)d_in[10];
  const float* mp_b = (const float*)d_in[11];
  const float* ln_w = (const float*)d_in[12];
  const float* ln_b = (const float*)d_in[13];
  const float* ng_w1 = (const float*)d_in[14];
  const float* ng_b1 = (const float*)d_in[15];
  const float* ng_w2 = (const float*)d_in[16];
  const float* ng_b2 = (const float*)d_in[17];
  const float* ep_w  = (const float*)d_in[20];
  const float* ep_b  = (const float*)d_in[21];
  const float* cp_w1 = (const float*)d_in[22];
  const float* cp_b1 = (const float*)d_in[23];
  const float* cp_w2 = (const float*)d_in[24];
  const float* cp_b2 = (const float*)d_in[25];
  const float* np_w  = (const float*)d_in[26];
  const float* np_b  = (const float*)d_in[27];

  float* out = (float*)d_out;
  float* ws = (float*)d_ws;
  float* qvec    = ws + OFF_QVEC;
  float* qkT     = ws + OFF_QKT;
  float* qb      = ws + OFF_QB;
  float* lpart   = ws + OFF_LPART;
  float* ctx     = ws + OFF_CTX;
  float* trep    = ws + OFF_TREP;
  float* tmg     = ws + OFF_TM;
  float* nmg     = ws + OFF_NMG;
  float* partial = ws + OFF_PART;
  int* bar_counter = (int*)(ws + OFF_BAR);
  unsigned int* bar_gen = (unsigned int*)(ws + OFF_BAR + 1);

  hipMemsetAsync(ws + OFF_BAR, 0, 16, stream);
  k_qvec<<<256, 256, 0, stream>>>(tq, wq, bq, qvec);
  k_qk<<<32, 256, 0, stream>>>(qvec, wk, bk, qkT, qb);
  k_fused<<<512, 256, 0, stream>>>(x, qkT, qb, partial, lpart);
  k_tailp<<<TAIL_BLOCKS, 256, 0, stream>>>(
      partial, lpart, wv, bv, wo, bo, mp_w, mp_b, ln_w, ln_b, ng_w1, ng_b1,
      ng_w2, ng_b2, ep_w, ep_b, cp_w1, cp_b1, cp_w2, cp_b2, np_w, np_b,
      ctx, trep, tmg, nmg, bar_counter, bar_gen, out);
}

// Round 9
// 300.948 us; speedup vs baseline: 1.0257x; 1.0257x over previous
//
#include <hip/hip_runtime.h>
#include <hip/hip_bf16.h>

// ForcedDAGPlanner: B=16,S=4096,E=1024,M=64,N=32,H=8,D=128
// R9: weight-folding round. ctx->trep->tm collapses:
//   W2[m][j]   = sum_i mp_w[m][i]*wo[i][j]            (stored W2T[j][m])
//   W3[m][h][e]= sum_{jj} W2[m][h*128+jj]*wv[h*128+jj][e]
//   bias2[m]   = mp_w[m]·bo + mp_b[m] + W2[m]·bv      (split b2a + b2b)
//   tm_pre[b][m] = sum_{h,e} W3[m][h][e]*linv[b][h]*xa_u[b][h][e] + bias2[m]
// 6 graph nodes. No grid barriers (r8: 210us, latency-bound at 1 blk/CU — dead end).

#define DEVFN __device__ __forceinline__

constexpr float SCALE = 0.08838834764831845f; // 1/sqrt(128)

// workspace offsets (floats)
constexpr size_t OFF_QVEC  = 0;        // 1024
constexpr size_t OFF_QKT   = 1024;     // 8192  [h*1024+e]
constexpr size_t OFF_QB    = 9216;     // 8
constexpr size_t OFF_LPART = 9224;     // 4096  [cid*8+h]
constexpr size_t OFF_W2T   = 13320;    // 65536  [j][m]
constexpr size_t OFF_W3    = 78856;    // 524288 [m][h][e]
constexpr size_t OFF_B2A   = 603144;   // 64
constexpr size_t OFF_B2B   = 603208;   // 64
constexpr size_t OFF_TM    = 603272;   // 1024
constexpr size_t OFF_NMG   = 604296;   // 32768
constexpr size_t OFF_PART  = 637064;   // 512*8*1024 = 4194304 [cid][h][e]
// total ~19.3 MB of d_ws

// output offsets (f32 elements)
constexpr size_t OUT_EMB  = 0;        // 16*32*1024
constexpr size_t OUT_ADJ  = 524288;   // 16*32*32
constexpr size_t OUT_SURF = 540672;   // 16
constexpr size_t OUT_CPLX = 540688;   // 16*32
constexpr size_t OUT_MASK = 541200;   // 16*32

DEVFN float gelu_exact(float x) {
  return 0.5f * x * (1.0f + erff(x * 0.70710678118654752f));
}
DEVFN float softplus_f(float x) {
  return fmaxf(x, 0.0f) + log1pf(expf(-fabsf(x)));
}
DEVFN float dot4(float4 a, float4 b) {
  return a.x * b.x + a.y * b.y + a.z * b.z + a.w * b.w;
}

// ---- K1: pre1 = {qvec (blocks 0..255)} ∥ {W2T (blocks 256..319)}
__global__ __launch_bounds__(256) void k_pre1(
    const float* __restrict__ tq, const float* __restrict__ wq,
    const float* __restrict__ bq, const float* __restrict__ wo,
    const float* __restrict__ mp_w, float* __restrict__ qvec,
    float* __restrict__ w2t) {
  __shared__ float s_w2[4][64][17];  // padded: no bank conflict
  int t = threadIdx.x, wid = t >> 6, lane = t & 63;
  if (blockIdx.x < 256) {
    // qvec[i] = tq · wq[i,:] + bq[i]
    int i = blockIdx.x * 4 + wid;
    const float* wrow = wq + (size_t)i * 1024;
    float acc = 0.f;
#pragma unroll
    for (int k = 0; k < 4; ++k) {
      int e = lane * 4 + k * 256;
      acc += dot4(*(const float4*)(tq + e), *(const float4*)(wrow + e));
    }
#pragma unroll
    for (int off = 32; off; off >>= 1) acc += __shfl_xor(acc, off);
    if (lane == 0) qvec[i] = acc + bq[i];
    return;
  }
  // W2T[j][m] = sum_i mp_w[m][i]*wo[i][j]; block: j-block(64) x m-chunk(16),
  // wave = i-quarter(256). mp_w loads are lane-uniform -> scalar path.
  int idx = blockIdx.x - 256;         // 0..63
  int jb = idx & 15, mc = idx >> 4;
  int j = jb * 64 + lane;
  float acc[16];
#pragma unroll
  for (int mm = 0; mm < 16; ++mm) acc[mm] = 0.f;
  const float* wop = wo + (size_t)(wid * 256) * 1024 + j;
  const float* mpp = mp_w + (size_t)(mc * 16) * 1024 + wid * 256;
  for (int i = 0; i < 256; ++i) {
    float wov = wop[(size_t)i * 1024];
#pragma unroll
    for (int mm = 0; mm < 16; ++mm)
      acc[mm] += mpp[(size_t)mm * 1024 + i] * wov;
  }
#pragma unroll
  for (int mm = 0; mm < 16; ++mm) s_w2[wid][lane][mm] = acc[mm];
  __syncthreads();
  int jj = t >> 2, mq = (t & 3) * 4;
  float4 s = make_float4(0.f, 0.f, 0.f, 0.f);
#pragma unroll
  for (int w = 0; w < 4; ++w) {
    s.x += s_w2[w][jj][mq + 0];
    s.y += s_w2[w][jj][mq + 1];
    s.z += s_w2[w][jj][mq + 2];
    s.w += s_w2[w][jj][mq + 3];
  }
  *(float4*)(w2t + (size_t)(jb * 64 + jj) * 64 + mc * 16 + mq) = s;
}

// ---- K2: pre2 = {qk (0..31)} ∥ {W3 (32..95)} ∥ {b2a (96)} ∥ {b2b (97)}
__global__ __launch_bounds__(256) void k_pre2(
    const float* __restrict__ qvec, const float* __restrict__ wk,
    const float* __restrict__ bk, const float* __restrict__ wv,
    const float* __restrict__ bv, const float* __restrict__ bo,
    const float* __restrict__ mp_w, const float* __restrict__ mp_b,
    const float* __restrict__ w2t, float* __restrict__ qkT,
    float* __restrict__ qb, float* __restrict__ w3,
    float* __restrict__ b2a, float* __restrict__ b2b) {
  __shared__ float smem[256];
  int blk = blockIdx.x, t = threadIdx.x, wid = t >> 6, lane = t & 63;
  if (blk < 32) {
    // qkT[h*1024+e], qb[h]
    __shared__ float qh[128];
    int h = blk >> 2, e0 = (blk & 3) * 256;
    if (t < 128) qh[t] = qvec[h * 128 + t];
    __syncthreads();
    int e = e0 + t;
    float acc = 0.f;
#pragma unroll 32
    for (int d = 0; d < 128; ++d)
      acc += qh[d] * wk[(size_t)(h * 128 + d) * 1024 + e];
    qkT[h * 1024 + e] = acc * SCALE;
    if (t == 0 && e0 == 0) {
      float s = 0.f;
      for (int d = 0; d < 128; ++d) s += qh[d] * bk[h * 128 + d];
      qb[h] = s * SCALE;
    }
    return;
  }
  if (blk < 96) {
    // W3[(m)(8)+h][e] for m-half mh: 32 register accumulators; W2T loads are
    // lane-uniform (contiguous 64-float rows) -> scalar path.
    int idx = blk - 32;                       // 0..63
    int h = idx >> 3, ec = (idx >> 1) & 3, mh = idx & 1;
    int e = ec * 256 + t;
    float acc[32];
#pragma unroll
    for (int m = 0; m < 32; ++m) acc[m] = 0.f;
    const float* wvp = wv + (size_t)(h * 128) * 1024 + e;
    const float* w2p = w2t + (size_t)(h * 128) * 64 + mh * 32;
    for (int jjj = 0; jjj < 128; ++jjj) {
      float wvv = wvp[(size_t)jjj * 1024];
      const float* w2row = w2p + (size_t)jjj * 64;
#pragma unroll
      for (int m = 0; m < 32; ++m) acc[m] += w2row[m] * wvv;
    }
#pragma unroll
    for (int m = 0; m < 32; ++m)
      w3[((size_t)(mh * 32 + m) * 8 + h) * 1024 + e] = acc[m];
    return;
  }
  if (blk == 96) {
    // b2a[m] = sum_j bv[j] * W2T[j][m]
    float acc[64];
#pragma unroll
    for (int m = 0; m < 64; ++m) acc[m] = 0.f;
#pragma unroll
    for (int jq = 0; jq < 4; ++jq) {
      int j = t * 4 + jq;
      float bvj = bv[j];
      const float* row = w2t + (size_t)j * 64;
#pragma unroll
      for (int k = 0; k < 16; ++k) {
        float4 r = *(const float4*)(row + k * 4);
        acc[k * 4 + 0] += bvj * r.x;
        acc[k * 4 + 1] += bvj * r.y;
        acc[k * 4 + 2] += bvj * r.z;
        acc[k * 4 + 3] += bvj * r.w;
      }
    }
#pragma unroll
    for (int m = 0; m < 64; ++m) {
#pragma unroll
      for (int off = 32; off; off >>= 1) acc[m] += __shfl_xor(acc[m], off);
    }
    if (lane == 0) {
#pragma unroll
      for (int m = 0; m < 64; ++m) smem[wid * 64 + m] = acc[m];
    }
    __syncthreads();
    if (t < 64)
      b2a[t] = smem[t] + smem[64 + t] + smem[128 + t] + smem[192 + t];
    return;
  }
  // blk == 97: b2b[m] = mp_w[m]·bo + mp_b[m]
  for (int it = 0; it < 16; ++it) {
    int m = wid * 16 + it;
    const float* wr = mp_w + (size_t)m * 1024 + lane * 4;
    const float* br = bo + lane * 4;
    float a = 0.f;
#pragma unroll
    for (int k = 0; k < 4; ++k)
      a += dot4(*(const float4*)(wr + k * 256), *(const float4*)(br + k * 256));
#pragma unroll
    for (int off = 32; off; off >>= 1) a += __shfl_xor(a, off);
    if (lane == 0) b2b[m] = a + mp_b[m];
  }
}

// ---- K3: fused score+exp+weighted-sum, single x pass (r7/r8 proven).
__global__ __launch_bounds__(256, 2) void k_fused(
    const float* __restrict__ x, const float* __restrict__ qkT,
    const float* __restrict__ qb, float* __restrict__ partial,
    float* __restrict__ lpart) {
  __shared__ __align__(16) float lds[8 * 1024];
  __shared__ float s_ll[8];
  int t = threadIdx.x, wid = t >> 6, lane = t & 63;
  int rh = wid >> 1, hg = wid & 1;

  float4 qr[4][4];
#pragma unroll
  for (int hh = 0; hh < 4; ++hh)
#pragma unroll
    for (int k = 0; k < 4; ++k)
      qr[hh][k] = *(const float4*)(qkT + (hg * 4 + hh) * 1024 + k * 256 + lane * 4);
  float qbr[4];
#pragma unroll
  for (int hh = 0; hh < 4; ++hh) qbr[hh] = qb[hg * 4 + hh];

  float4 acc[4][4];
#pragma unroll
  for (int hh = 0; hh < 4; ++hh)
#pragma unroll
    for (int k = 0; k < 4; ++k) acc[hh][k] = make_float4(0.f, 0.f, 0.f, 0.f);
  float lsum[4] = {0.f, 0.f, 0.f, 0.f};

  int row0 = blockIdx.x * 128 + rh * 64;
  const float* xr = x + ((size_t)row0 << 10) + lane * 4;
  float4 A0 = *(const float4*)(xr + 0);
  float4 A1 = *(const float4*)(xr + 256);
  float4 A2 = *(const float4*)(xr + 512);
  float4 A3 = *(const float4*)(xr + 768);
  float4 B0 = *(const float4*)(xr + 1024);
  float4 B1 = *(const float4*)(xr + 1280);
  float4 B2 = *(const float4*)(xr + 1536);
  float4 B3 = *(const float4*)(xr + 1792);

  for (int r = 0; r < 64; ++r) {
    float4 c0 = A0, c1 = A1, c2 = A2, c3 = A3;
    A0 = B0; A1 = B1; A2 = B2; A3 = B3;
    if (r < 62) {
      const float* nx = xr + ((size_t)(r + 2) << 10);
      B0 = *(const float4*)(nx + 0);
      B1 = *(const float4*)(nx + 256);
      B2 = *(const float4*)(nx + 512);
      B3 = *(const float4*)(nx + 768);
    }
    float s[4];
#pragma unroll
    for (int hh = 0; hh < 4; ++hh)
      s[hh] = dot4(c0, qr[hh][0]) + dot4(c1, qr[hh][1]) +
              dot4(c2, qr[hh][2]) + dot4(c3, qr[hh][3]);
#pragma unroll
    for (int off = 1; off <= 32; off <<= 1)
#pragma unroll
      for (int hh = 0; hh < 4; ++hh) s[hh] += __shfl_xor(s[hh], off);
    float w[4];
#pragma unroll
    for (int hh = 0; hh < 4; ++hh) {
      w[hh] = expf(s[hh] + qbr[hh]);
      lsum[hh] += w[hh];
    }
#pragma unroll
    for (int hh = 0; hh < 4; ++hh) {
      acc[hh][0].x += w[hh] * c0.x; acc[hh][0].y += w[hh] * c0.y;
      acc[hh][0].z += w[hh] * c0.z; acc[hh][0].w += w[hh] * c0.w;
      acc[hh][1].x += w[hh] * c1.x; acc[hh][1].y += w[hh] * c1.y;
      acc[hh][1].z += w[hh] * c1.z; acc[hh][1].w += w[hh] * c1.w;
      acc[hh][2].x += w[hh] * c2.x; acc[hh][2].y += w[hh] * c2.y;
      acc[hh][2].z += w[hh] * c2.z; acc[hh][2].w += w[hh] * c2.w;
      acc[hh][3].x += w[hh] * c3.x; acc[hh][3].y += w[hh] * c3.y;
      acc[hh][3].z += w[hh] * c3.z; acc[hh][3].w += w[hh] * c3.w;
    }
  }
  if (rh == 1) {
#pragma unroll
    for (int hh = 0; hh < 4; ++hh)
#pragma unroll
      for (int k = 0; k < 4; ++k)
        *(float4*)(lds + (hg * 4 + hh) * 1024 + k * 256 + lane * 4) = acc[hh][k];
    if (lane == 0)
#pragma unroll
      for (int hh = 0; hh < 4; ++hh) s_ll[hg * 4 + hh] = lsum[hh];
  }
  __syncthreads();
  if (rh == 0) {
    size_t base = (((size_t)blockIdx.x * 8 + hg * 4) << 10) + lane * 4;
#pragma unroll
    for (int hh = 0; hh < 4; ++hh)
#pragma unroll
      for (int k = 0; k < 4; ++k) {
        const float4 o = *(const float4*)(lds + (hg * 4 + hh) * 1024 + k * 256 + lane * 4);
        float4 v = acc[hh][k];
        v.x += o.x; v.y += o.y; v.z += o.z; v.w += o.w;
        *(float4*)(partial + base + ((size_t)hh << 10) + k * 256) = v;
      }
    if (lane == 0)
#pragma unroll
      for (int hh = 0; hh < 4; ++hh)
        lpart[blockIdx.x * 8 + hg * 4 + hh] = lsum[hh] + s_ll[hg * 4 + hh];
  }
}

// ---- K4: tmb. 64 blocks = (b, m-chunk 16). Reduce+scale xa into LDS, then
// 16 wave-dots of 8192 against W3 rows. tm_pre written.
__global__ __launch_bounds__(256) void k_tmb(
    const float* __restrict__ partial, const float* __restrict__ lpart,
    const float* __restrict__ w3, const float* __restrict__ b2a,
    const float* __restrict__ b2b, float* __restrict__ tmg) {
  __shared__ __align__(16) float s_xa[8192];
  __shared__ float s_red[32];
  __shared__ float s_linv[8];
  int blk = blockIdx.x, b = blk >> 2, mc = blk & 3;
  int t = threadIdx.x, wid = t >> 6, lane = t & 63;
  // linv[h] = 1 / sum_c lpart[(b*32+c)*8+h]
  {
    int h = lane & 7, c = wid * 8 + (lane >> 3);
    float v = lpart[(size_t)(b * 32 + c) * 8 + h];
    v += __shfl_xor(v, 8);
    v += __shfl_xor(v, 16);
    v += __shfl_xor(v, 32);
    if (lane < 8) s_red[wid * 8 + lane] = v;
    __syncthreads();
    if (t < 8)
      s_linv[t] = 1.0f / (s_red[t] + s_red[8 + t] + s_red[16 + t] + s_red[24 + t]);
    __syncthreads();
  }
  // stage xa scaled by linv
  for (int h = 0; h < 8; ++h) {
    float4 a = make_float4(0.f, 0.f, 0.f, 0.f);
    const float* pp = partial + (size_t)b * 262144 + h * 1024 + t * 4;
#pragma unroll 8
    for (int c = 0; c < 32; ++c) {
      float4 v = *(const float4*)(pp + (size_t)c * 8192);
      a.x += v.x; a.y += v.y; a.z += v.z; a.w += v.w;
    }
    float li = s_linv[h];
    a.x *= li; a.y *= li; a.z *= li; a.w *= li;
    *(float4*)(s_xa + h * 1024 + t * 4) = a;
  }
  __syncthreads();
  // 4 m per wave: tm_pre[b][m] = W3[m]·s_xa + b2a[m] + b2b[m]
  for (int q = 0; q < 4; ++q) {
    int m = mc * 16 + wid * 4 + q;
    const float* w3r = w3 + (size_t)m * 8192 + lane * 4;
    const float* xr = s_xa + lane * 4;
    float a = 0.f;
#pragma unroll
    for (int k = 0; k < 32; ++k)
      a += dot4(*(const float4*)(w3r + k * 256), *(const float4*)(xr + k * 256));
#pragma unroll
    for (int off = 32; off; off >>= 1) a += __shfl_xor(a, off);
    if (lane == 0) tmg[b * 64 + m] = a + b2a[m] + b2b[m];
  }
}

// ---- K5: nm (r8-P4 coalesced form). 128 blocks = (b, nodegroup of 4).
__global__ __launch_bounds__(256) void k_nm(
    const float* __restrict__ tmg, const float* __restrict__ ln_w,
    const float* __restrict__ ln_b, const float* __restrict__ ng_w1,
    const float* __restrict__ ng_b1, const float* __restrict__ ng_w2,
    const float* __restrict__ ng_b2, float* __restrict__ nmg) {
  __shared__ float s_tm[64];
  __shared__ float s_h2[128];
  __shared__ float s_np[256];
  int b = blockIdx.x >> 3, ng = blockIdx.x & 7;
  int t = threadIdx.x, wid = t >> 6, lane = t & 63;
  if (wid == 0) {
    float v = tmg[b * 64 + lane];
    float sm = v;
#pragma unroll
    for (int off = 32; off; off >>= 1) sm += __shfl_xor(sm, off);
    float mu = sm * (1.f / 64.f);
    float d = v - mu;
    float vv = d * d;
#pragma unroll
    for (int off = 32; off; off >>= 1) vv += __shfl_xor(vv, off);
    float rstd = 1.f / sqrtf(vv * (1.f / 64.f) + 1e-5f);
    s_tm[lane] = d * rstd * ln_w[lane] + ln_b[lane];
  }
  __syncthreads();
  if (t < 128) {
    float acc = ng_b1[t];
    const float* wr = ng_w1 + (size_t)t * 64;
#pragma unroll 16
    for (int m = 0; m < 64; ++m) acc += s_tm[m] * wr[m];
    s_h2[t] = gelu_exact(acc);
  }
  __syncthreads();
  int half = lane >> 5, hl = lane & 31;
  float4 hv4 = *(const float4*)(s_h2 + hl * 4);
  for (int it = 0; it < 32; ++it) {
    int ol = wid * 64 + it * 2 + half;   // 0..255
    int o = ng * 256 + ol;               // ng_w2 row 0..2047
    float4 wv4 = *(const float4*)(ng_w2 + (size_t)o * 128 + hl * 4);
    float a = dot4(wv4, hv4);
#pragma unroll
    for (int off = 1; off <= 16; off <<= 1) a += __shfl_xor(a, off);
    if (hl == 0) s_np[ol] = a + ng_b2[o];
  }
  __syncthreads();
  {
    float v = s_np[wid * 64 + lane];
    float sm = v;
#pragma unroll
    for (int off = 32; off; off >>= 1) sm += __shfl_xor(sm, off);
    float mu = sm * (1.f / 64.f);
    float d = v - mu;
    float vv = d * d;
#pragma unroll
    for (int off = 32; off; off >>= 1) vv += __shfl_xor(vv, off);
    float rstd = 1.f / sqrtf(vv * (1.f / 64.f) + 1e-5f);
    nmg[b * 2048 + (ng * 4 + wid) * 64 + lane] =
        d * rstd * ln_w[lane] + ln_b[lane];
  }
}

// ---- K6: heads (blocks 0..15) + node embeddings (blocks 16..79)
__global__ __launch_bounds__(256) void k_he(
    const float* __restrict__ nmg, const float* __restrict__ ep_w,
    const float* __restrict__ ep_b, const float* __restrict__ cp_w1,
    const float* __restrict__ cp_b1, const float* __restrict__ cp_w2,
    const float* __restrict__ cp_b2, const float* __restrict__ np_w,
    const float* __restrict__ np_b, float* __restrict__ out) {
  __shared__ __align__(16) float s_nm[2048];
  __shared__ float s_t[2048];
  __shared__ float s_c1[1024];
  __shared__ float s_cx[32];
  int t = threadIdx.x, wid = t >> 6, lane = t & 63;
  if (blockIdx.x < 16) {
    int b = blockIdx.x;
    for (int i = t; i < 512; i += 256)
      ((float4*)s_nm)[i] = ((const float4*)(nmg + (size_t)b * 2048))[i];
    __syncthreads();
    for (int o = t; o < 1024; o += 256) {
      int i = o >> 5, r = o & 31;
      float acc = cp_b1[r];
      const float* wr = cp_w1 + (size_t)r * 64;
#pragma unroll 8
      for (int m = 0; m < 64; ++m) acc += s_nm[i * 64 + m] * wr[m];
      s_c1[o] = gelu_exact(acc);
    }
    __syncthreads();
    if (t < 32) {
      float acc = cp_b2[0];
#pragma unroll 8
      for (int r = 0; r < 32; ++r) acc += s_c1[t * 32 + r] * cp_w2[r];
      float sp = softplus_f(acc);
      s_cx[t] = sp;
      out[OUT_CPLX + b * 32 + t] = sp;
      out[OUT_MASK + b * 32 + t] = 1.0f;
    }
    __syncthreads();
    if (wid == 0) {
      float v = (lane < 32) ? s_cx[lane] : 0.f;
#pragma unroll
      for (int off = 32; off; off >>= 1) v += __shfl_xor(v, off);
      if (lane == 0) out[OUT_SURF + b] = v;
    }
    for (int o = t; o < 2048; o += 256) {
      int i = o >> 6, n = o & 63;
      float acc = 0.f;
#pragma unroll 8
      for (int m = 0; m < 64; ++m) acc += s_nm[i * 64 + m] * ep_w[m * 64 + n];
      s_t[o] = acc;
    }
    __syncthreads();
    for (int o = t; o < 1024; o += 256) {
      int i = o >> 5, j = o & 31;
      float acc = ep_b[0];
#pragma unroll 8
      for (int n = 0; n < 64; ++n) acc += s_t[i * 64 + n] * s_nm[j * 64 + n];
      float sg = 1.f / (1.f + expf(-acc));
      float val = (j > i && sg > 0.3f) ? 1.f : 0.f;
      out[OUT_ADJ + (size_t)b * 1024 + i * 32 + j] = val;
    }
  } else {
    int idx = blockIdx.x - 16;  // 64 blocks
    int b = idx >> 2, e0 = (idx & 3) * 256;
    *(float4*)(s_nm + t * 4) = *(const float4*)(nmg + b * 2048 + t * 4);
    *(float4*)(s_nm + 1024 + t * 4) =
        *(const float4*)(nmg + b * 2048 + 1024 + t * 4);
    __syncthreads();
    int e = e0 + t;
    float4 w[16];
    const float* wr = np_w + (size_t)e * 64;
#pragma unroll
    for (int k = 0; k < 16; ++k) w[k] = *(const float4*)(wr + k * 4);
    float bias = np_b[e];
    for (int i = 0; i < 32; ++i) {
      float acc = bias;
#pragma unroll
      for (int k = 0; k < 16; ++k)
        acc += dot4(w[k], *(const float4*)(s_nm + i * 64 + k * 4));
      out[OUT_EMB + (size_t)(b * 32 + i) * 1024 + e] = acc;
    }
  }
}

extern "C" void kernel_launch(void* const* d_in, const int* in_sizes, int n_in,
                              void* d_out, int out_size, void* d_ws, size_t ws_size,
                              hipStream_t stream) {
  (void)in_sizes; (void)n_in; (void)out_size; (void)ws_size;
  const float* x    = (const float*)d_in[0];
  const float* tq   = (const float*)d_in[1];
  const float* wq   = (const float*)d_in[2];
  const float* bq   = (const float*)d_in[3];
  const float* wk   = (const float*)d_in[4];
  const float* bk   = (const float*)d_in[5];
  const float* wv   = (const float*)d_in[6];
  const float* bv   = (const float*)d_in[7];
  const float* wo   = (const float*)d_in[8];
  const float* bo   = (const float*)d_in[9];
  const float* mp_w = (const float*)d_in[10];
  const float* mp_b = (const float*)d_in[11];
  const float* ln_w = (const float*)d_in[12];
  const float* ln_b = (const float*)d_in[13];
  const float* ng_w1 = (const float*)d_in[14];
  const float* ng_b1 = (const float*)d_in[15];
  const float* ng_w2 = (const float*)d_in[16];
  const float* ng_b2 = (const float*)d_in[17];
  const float* ep_w  = (const float*)d_in[20];
  const float* ep_b  = (const float*)d_in[21];
  const float* cp_w1 = (const float*)d_in[22];
  const float* cp_b1 = (const float*)d_in[23];
  const float* cp_w2 = (const float*)d_in[24];
  const float* cp_b2 = (const float*)d_in[25];
  const float* np_w  = (const float*)d_in[26];
  const float* np_b  = (const float*)d_in[27];

  float* out = (float*)d_out;
  float* ws = (float*)d_ws;
  float* qvec    = ws + OFF_QVEC;
  float* qkT     = ws + OFF_QKT;
  float* qb      = ws + OFF_QB;
  float* lpart   = ws + OFF_LPART;
  float* w2t     = ws + OFF_W2T;
  float* w3      = ws + OFF_W3;
  float* b2a     = ws + OFF_B2A;
  float* b2b     = ws + OFF_B2B;
  float* tmg     = ws + OFF_TM;
  float* nmg     = ws + OFF_NMG;
  float* partial = ws + OFF_PART;

  k_pre1<<<320, 256, 0, stream>>>(tq, wq, bq, wo, mp_w, qvec, w2t);
  k_pre2<<<98, 256, 0, stream>>>(qvec, wk, bk, wv, bv, bo, mp_w, mp_b, w2t,
                                 qkT, qb, w3, b2a, b2b);
  k_fused<<<512, 256, 0, stream>>>(x, qkT, qb, partial, lpart);
  k_tmb<<<64, 256, 0, stream>>>(partial, lpart, w3, b2a, b2b, tmg);
  k_nm<<<128, 256, 0, stream>>>(tmg, ln_w, ln_b, ng_w1, ng_b1, ng_w2, ng_b2, nmg);
  k_he<<<80, 256, 0, stream>>>(nmg, ep_w, ep_b, cp_w1, cp_b1, cp_w2, cp_b2,
                               np_w, np_b, out);
}

// Round 10
// 195.258 us; speedup vs baseline: 1.5809x; 1.5413x over previous
//
#include <hip/hip_runtime.h>
#include <hip/hip_bf16.h>

// ForcedDAGPlanner: B=16,S=4096,E=1024,M=64,N=32,H=8,D=128
//   scores[b,h,s] = x[b,s,:]·qk[h,:] + qb[h]   (qk = (q·Wk)/sqrt(D), 8x1024)
//   xa[b,h,:]     = softmax-weighted sum of x rows (unnormalized partials + l)
//   ctx[b,j]      = xa[b,h(j),:]·wv[j,:] + bv[j]
//   k_nodes = 32 -> node_mask all-true.
// R10: r7 structure (178us best) with qvec+qk merged into one 32-block kernel
// (qvec recomputed per-head redundantly). 7 launches. Decisive span-vs-fill test:
// harness re-poisons d_ws (1GiB fill ~151us @7TB/s) every replay, sharing HBM.

#define DEVFN __device__ __forceinline__

constexpr float SCALE = 0.08838834764831845f; // 1/sqrt(128)

// workspace offsets (floats)
constexpr size_t OFF_QKT   = 0;        // 8192  [h*1024+e]
constexpr size_t OFF_QB    = 8192;     // 8
constexpr size_t OFF_LPART = 8200;     // 4096  [cid*8+h]
constexpr size_t OFF_CTX   = 12296;    // 16384
constexpr size_t OFF_TREP  = 28680;    // 16384
constexpr size_t OFF_TM    = 45064;    // 1024
constexpr size_t OFF_NMG   = 46088;    // 32768
constexpr size_t OFF_PART  = 78856;    // 512*8*1024 = 4194304 [cid][h][e]
// total ~17.1 MB of d_ws

// output offsets (f32 elements)
constexpr size_t OUT_EMB  = 0;        // 16*32*1024
constexpr size_t OUT_ADJ  = 524288;   // 16*32*32
constexpr size_t OUT_SURF = 540672;   // 16
constexpr size_t OUT_CPLX = 540688;   // 16*32
constexpr size_t OUT_MASK = 541200;   // 16*32

DEVFN float gelu_exact(float x) {
  return 0.5f * x * (1.0f + erff(x * 0.70710678118654752f));
}
DEVFN float softplus_f(float x) {
  return fmaxf(x, 0.0f) + log1pf(expf(-fabsf(x)));
}
DEVFN float dot4(float4 a, float4 b) {
  return a.x * b.x + a.y * b.y + a.z * b.z + a.w * b.w;
}

// ---- K0: merged qvec+qk. 32 blocks = (h, e-chunk). Phase 1: qh[128] computed
// redundantly per block (wave-dots over wq). Phase 2: qkT e-slice + qb.
__global__ __launch_bounds__(256) void k_qkq(
    const float* __restrict__ tq, const float* __restrict__ wq,
    const float* __restrict__ bq, const float* __restrict__ wk,
    const float* __restrict__ bk, float* __restrict__ qkT,
    float* __restrict__ qb) {
  __shared__ float qh[128];
  int h = blockIdx.x >> 2, ec = blockIdx.x & 3;
  int t = threadIdx.x, wid = t >> 6, lane = t & 63;
  for (int it = 0; it < 32; ++it) {
    int d = wid * 32 + it;
    const float* wrow = wq + (size_t)(h * 128 + d) * 1024;
    float acc = 0.f;
#pragma unroll
    for (int k = 0; k < 4; ++k) {
      int e = lane * 4 + k * 256;
      acc += dot4(*(const float4*)(tq + e), *(const float4*)(wrow + e));
    }
#pragma unroll
    for (int off = 32; off; off >>= 1) acc += __shfl_xor(acc, off);
    if (lane == 0) qh[d] = acc + bq[h * 128 + d];
  }
  __syncthreads();
  int e = ec * 256 + t;
  float acc = 0.f;
#pragma unroll 32
  for (int d = 0; d < 128; ++d)
    acc += qh[d] * wk[(size_t)(h * 128 + d) * 1024 + e];
  qkT[h * 1024 + e] = acc * SCALE;
  if (t == 0 && ec == 0) {
    float s = 0.f;
    for (int d = 0; d < 128; ++d) s += qh[d] * bk[h * 128 + d];
    qb[h] = s * SCALE;
  }
}

// ---- K1 v4 (r7 verbatim): fused score+exp+weighted-sum, single x pass.
__global__ __launch_bounds__(256, 2) void k_fused(
    const float* __restrict__ x, const float* __restrict__ qkT,
    const float* __restrict__ qb, float* __restrict__ partial,
    float* __restrict__ lpart) {
  __shared__ __align__(16) float lds[8 * 1024];
  __shared__ float s_ll[8];
  int t = threadIdx.x, wid = t >> 6, lane = t & 63;
  int rh = wid >> 1, hg = wid & 1;

  float4 qr[4][4];
#pragma unroll
  for (int hh = 0; hh < 4; ++hh)
#pragma unroll
    for (int k = 0; k < 4; ++k)
      qr[hh][k] = *(const float4*)(qkT + (hg * 4 + hh) * 1024 + k * 256 + lane * 4);
  float qbr[4];
#pragma unroll
  for (int hh = 0; hh < 4; ++hh) qbr[hh] = qb[hg * 4 + hh];

  float4 acc[4][4];
#pragma unroll
  for (int hh = 0; hh < 4; ++hh)
#pragma unroll
    for (int k = 0; k < 4; ++k) acc[hh][k] = make_float4(0.f, 0.f, 0.f, 0.f);
  float lsum[4] = {0.f, 0.f, 0.f, 0.f};

  int row0 = blockIdx.x * 128 + rh * 64;
  const float* xr = x + ((size_t)row0 << 10) + lane * 4;
  float4 A0 = *(const float4*)(xr + 0);
  float4 A1 = *(const float4*)(xr + 256);
  float4 A2 = *(const float4*)(xr + 512);
  float4 A3 = *(const float4*)(xr + 768);
  float4 B0 = *(const float4*)(xr + 1024);
  float4 B1 = *(const float4*)(xr + 1280);
  float4 B2 = *(const float4*)(xr + 1536);
  float4 B3 = *(const float4*)(xr + 1792);

  for (int r = 0; r < 64; ++r) {
    float4 c0 = A0, c1 = A1, c2 = A2, c3 = A3;
    A0 = B0; A1 = B1; A2 = B2; A3 = B3;
    if (r < 62) {
      const float* nx = xr + ((size_t)(r + 2) << 10);
      B0 = *(const float4*)(nx + 0);
      B1 = *(const float4*)(nx + 256);
      B2 = *(const float4*)(nx + 512);
      B3 = *(const float4*)(nx + 768);
    }
    float s[4];
#pragma unroll
    for (int hh = 0; hh < 4; ++hh)
      s[hh] = dot4(c0, qr[hh][0]) + dot4(c1, qr[hh][1]) +
              dot4(c2, qr[hh][2]) + dot4(c3, qr[hh][3]);
#pragma unroll
    for (int off = 1; off <= 32; off <<= 1)
#pragma unroll
      for (int hh = 0; hh < 4; ++hh) s[hh] += __shfl_xor(s[hh], off);
    float w[4];
#pragma unroll
    for (int hh = 0; hh < 4; ++hh) {
      w[hh] = expf(s[hh] + qbr[hh]);
      lsum[hh] += w[hh];
    }
#pragma unroll
    for (int hh = 0; hh < 4; ++hh) {
      acc[hh][0].x += w[hh] * c0.x; acc[hh][0].y += w[hh] * c0.y;
      acc[hh][0].z += w[hh] * c0.z; acc[hh][0].w += w[hh] * c0.w;
      acc[hh][1].x += w[hh] * c1.x; acc[hh][1].y += w[hh] * c1.y;
      acc[hh][1].z += w[hh] * c1.z; acc[hh][1].w += w[hh] * c1.w;
      acc[hh][2].x += w[hh] * c2.x; acc[hh][2].y += w[hh] * c2.y;
      acc[hh][2].z += w[hh] * c2.z; acc[hh][2].w += w[hh] * c2.w;
      acc[hh][3].x += w[hh] * c3.x; acc[hh][3].y += w[hh] * c3.y;
      acc[hh][3].z += w[hh] * c3.z; acc[hh][3].w += w[hh] * c3.w;
    }
  }
  if (rh == 1) {
#pragma unroll
    for (int hh = 0; hh < 4; ++hh)
#pragma unroll
      for (int k = 0; k < 4; ++k)
        *(float4*)(lds + (hg * 4 + hh) * 1024 + k * 256 + lane * 4) = acc[hh][k];
    if (lane == 0)
#pragma unroll
      for (int hh = 0; hh < 4; ++hh) s_ll[hg * 4 + hh] = lsum[hh];
  }
  __syncthreads();
  if (rh == 0) {
    size_t base = (((size_t)blockIdx.x * 8 + hg * 4) << 10) + lane * 4;
#pragma unroll
    for (int hh = 0; hh < 4; ++hh)
#pragma unroll
      for (int k = 0; k < 4; ++k) {
        const float4 o = *(const float4*)(lds + (hg * 4 + hh) * 1024 + k * 256 + lane * 4);
        float4 v = acc[hh][k];
        v.x += o.x; v.y += o.y; v.z += o.z; v.w += o.w;
        *(float4*)(partial + base + ((size_t)hh << 10) + k * 256) = v;
      }
    if (lane == 0)
#pragma unroll
      for (int hh = 0; hh < 4; ++hh)
        lpart[blockIdx.x * 8 + hg * 4 + hh] = lsum[hh] + s_ll[hg * 4 + hh];
  }
}

// ---- K2: comb2+ctx fused (r7 verbatim). Block (b,h): reduce xa slice in LDS,
// then ctx[b, j in head h] = (xa_unnorm · wv[j,:]) * linv + bv[j]
__global__ __launch_bounds__(256) void k_combctx(
    const float* __restrict__ partial, const float* __restrict__ lpart,
    const float* __restrict__ wv, const float* __restrict__ bv,
    float* __restrict__ ctx) {
  __shared__ __align__(16) float s_xa[1024];
  __shared__ float s_linv;
  int bh = blockIdx.x, b = bh >> 3, h = bh & 7, t = threadIdx.x;
  float4 s4 = make_float4(0.f, 0.f, 0.f, 0.f);
#pragma unroll 8
  for (int c = 0; c < 32; ++c) {
    float4 v = *(const float4*)(partial +
        (((size_t)(b * 32 + c) * 8 + h) << 10) + t * 4);
    s4.x += v.x; s4.y += v.y; s4.z += v.z; s4.w += v.w;
  }
  *(float4*)(s_xa + t * 4) = s4;
  if (t == 0) {
    float s = 0.f;
#pragma unroll
    for (int c = 0; c < 32; ++c) s += lpart[(b * 32 + c) * 8 + h];
    s_linv = 1.0f / s;
  }
  __syncthreads();
  int wid = t >> 6, lane = t & 63;
  float linv = s_linv;
  for (int it = 0; it < 32; ++it) {
    int j = h * 128 + wid * 32 + it;
    const float* wr = wv + (size_t)j * 1024 + lane * 4;
    const float* xr = s_xa + lane * 4;
    float acc = 0.f;
#pragma unroll
    for (int k = 0; k < 4; ++k)
      acc += dot4(*(const float4*)(xr + k * 256), *(const float4*)(wr + k * 256));
#pragma unroll
    for (int off = 32; off; off >>= 1) acc += __shfl_xor(acc, off);
    if (lane == 0) ctx[b * 1024 + j] = acc * linv + bv[j];
  }
}

// ---- K3: task_repr (r7 verbatim). 1024 blocks, 16 outputs/block.
__global__ void k_trep(const float* __restrict__ ctx, const float* __restrict__ wo,
                       const float* __restrict__ bo, float* __restrict__ trep) {
  int wid = threadIdx.x >> 6, lane = threadIdx.x & 63;
#pragma unroll
  for (int it = 0; it < 4; ++it) {
    int gw = blockIdx.x * 16 + wid * 4 + it;
    int b = gw >> 10, i = gw & 1023;
    const float* xr = ctx + (size_t)b * 1024;
    const float* wr = wo + (size_t)i * 1024;
    float acc = 0.f;
#pragma unroll
    for (int k = 0; k < 4; ++k) {
      int e = lane * 4 + k * 256;
      acc += dot4(*(const float4*)(xr + e), *(const float4*)(wr + e));
    }
#pragma unroll
    for (int off = 32; off; off >>= 1) acc += __shfl_xor(acc, off);
    if (lane == 0) trep[b * 1024 + i] = acc + bo[i];
  }
}

// ---- K4: tm (r7 verbatim). 64 blocks.
__global__ void k_tm(const float* __restrict__ trep, const float* __restrict__ mp_w,
                     const float* __restrict__ mp_b, float* __restrict__ tmg) {
  int b = blockIdx.x >> 2, mc = blockIdx.x & 3;
  int wid = threadIdx.x >> 6, lane = threadIdx.x & 63;
  const float* xr = trep + (size_t)b * 1024 + lane * 4;
#pragma unroll
  for (int it = 0; it < 4; ++it) {
    int m = mc * 16 + wid * 4 + it;
    const float* wr = mp_w + (size_t)m * 1024 + lane * 4;
    float acc = 0.f;
#pragma unroll
    for (int k = 0; k < 4; ++k)
      acc += dot4(*(const float4*)(xr + k * 256), *(const float4*)(wr + k * 256));
#pragma unroll
    for (int off = 32; off; off >>= 1) acc += __shfl_xor(acc, off);
    if (lane == 0) tmg[b * 64 + m] = acc + mp_b[m];
  }
}

// ---- K5: nm (r7 verbatim). 256 blocks = (b, node-pair).
__global__ __launch_bounds__(256) void k_nm(
    const float* __restrict__ tmg, const float* __restrict__ ln_w,
    const float* __restrict__ ln_b, const float* __restrict__ ng_w1,
    const float* __restrict__ ng_b1, const float* __restrict__ ng_w2,
    const float* __restrict__ ng_b2, float* __restrict__ nmg) {
  __shared__ float s_tm[64];
  __shared__ float s_h2[128];
  __shared__ float s_np[128];
  int b = blockIdx.x >> 4, np = blockIdx.x & 15;
  int t = threadIdx.x, wid = t >> 6, lane = t & 63;
  if (wid == 0) {
    float v = tmg[b * 64 + lane];
    float sm = v;
#pragma unroll
    for (int off = 32; off; off >>= 1) sm += __shfl_xor(sm, off);
    float mu = sm * (1.f / 64.f);
    float d = v - mu;
    float vv = d * d;
#pragma unroll
    for (int off = 32; off; off >>= 1) vv += __shfl_xor(vv, off);
    float rstd = 1.f / sqrtf(vv * (1.f / 64.f) + 1e-5f);
    s_tm[lane] = d * rstd * ln_w[lane] + ln_b[lane];
  }
  __syncthreads();
  if (t < 128) {
    float acc = ng_b1[t];
    const float* wr = ng_w1 + (size_t)t * 64;
#pragma unroll 16
    for (int m = 0; m < 64; ++m) acc += s_tm[m] * wr[m];
    s_h2[t] = gelu_exact(acc);
  }
  __syncthreads();
  if (t < 128) {
    int o = np * 128 + t;
    float acc = ng_b2[o];
    const float* wr = ng_w2 + (size_t)o * 128;
#pragma unroll 8
    for (int r = 0; r < 128; ++r) acc += s_h2[r] * wr[r];
    s_np[t] = acc;
  }
  __syncthreads();
  if (wid < 2) {
    float v = s_np[wid * 64 + lane];
    float sm = v;
#pragma unroll
    for (int off = 32; off; off >>= 1) sm += __shfl_xor(sm, off);
    float mu = sm * (1.f / 64.f);
    float d = v - mu;
    float vv = d * d;
#pragma unroll
    for (int off = 32; off; off >>= 1) vv += __shfl_xor(vv, off);
    float rstd = 1.f / sqrtf(vv * (1.f / 64.f) + 1e-5f);
    nmg[b * 2048 + (np * 2 + wid) * 64 + lane] = d * rstd * ln_w[lane] + ln_b[lane];
  }
}

// ---- K6: merged heads (blocks 0..15) + node embeddings (blocks 16..79)
__global__ __launch_bounds__(256) void k_headsemb(
    const float* __restrict__ nmg, const float* __restrict__ ep_w,
    const float* __restrict__ ep_b, const float* __restrict__ cp_w1,
    const float* __restrict__ cp_b1, const float* __restrict__ cp_w2,
    const float* __restrict__ cp_b2, const float* __restrict__ np_w,
    const float* __restrict__ np_b, float* __restrict__ out) {
  __shared__ __align__(16) float s_nm[2048];
  __shared__ float s_t[2048];
  __shared__ float s_c1[1024];
  __shared__ float s_cx[32];
  int t = threadIdx.x, wid = t >> 6, lane = t & 63;
  if (blockIdx.x < 16) {
    int b = blockIdx.x;
    for (int i = t; i < 512; i += 256)
      ((float4*)s_nm)[i] = ((const float4*)(nmg + (size_t)b * 2048))[i];
    __syncthreads();
    for (int o = t; o < 1024; o += 256) {
      int i = o >> 5, r = o & 31;
      float acc = cp_b1[r];
      const float* wr = cp_w1 + (size_t)r * 64;
#pragma unroll 8
      for (int m = 0; m < 64; ++m) acc += s_nm[i * 64 + m] * wr[m];
      s_c1[o] = gelu_exact(acc);
    }
    __syncthreads();
    if (t < 32) {
      float acc = cp_b2[0];
#pragma unroll 8
      for (int r = 0; r < 32; ++r) acc += s_c1[t * 32 + r] * cp_w2[r];
      float sp = softplus_f(acc);
      s_cx[t] = sp;
      out[OUT_CPLX + b * 32 + t] = sp;
      out[OUT_MASK + b * 32 + t] = 1.0f;
    }
    __syncthreads();
    if (wid == 0) {
      float v = (lane < 32) ? s_cx[lane] : 0.f;
#pragma unroll
      for (int off = 32; off; off >>= 1) v += __shfl_xor(v, off);
      if (lane == 0) out[OUT_SURF + b] = v;
    }
    for (int o = t; o < 2048; o += 256) {
      int i = o >> 6, n = o & 63;
      float acc = 0.f;
#pragma unroll 8
      for (int m = 0; m < 64; ++m) acc += s_nm[i * 64 + m] * ep_w[m * 64 + n];
      s_t[o] = acc;
    }
    __syncthreads();
    for (int o = t; o < 1024; o += 256) {
      int i = o >> 5, j = o & 31;
      float acc = ep_b[0];
#pragma unroll 8
      for (int n = 0; n < 64; ++n) acc += s_t[i * 64 + n] * s_nm[j * 64 + n];
      float sg = 1.f / (1.f + expf(-acc));
      float val = (j > i && sg > 0.3f) ? 1.f : 0.f;
      out[OUT_ADJ + (size_t)b * 1024 + i * 32 + j] = val;
    }
  } else {
    int idx = blockIdx.x - 16;  // 64 blocks
    int b = idx >> 2, e0 = (idx & 3) * 256;
    *(float4*)(s_nm + t * 4) = *(const float4*)(nmg + b * 2048 + t * 4);
    *(float4*)(s_nm + 1024 + t * 4) =
        *(const float4*)(nmg + b * 2048 + 1024 + t * 4);
    __syncthreads();
    int e = e0 + t;
    float4 w[16];
    const float* wr = np_w + (size_t)e * 64;
#pragma unroll
    for (int k = 0; k < 16; ++k) w[k] = *(const float4*)(wr + k * 4);
    float bias = np_b[e];
    for (int i = 0; i < 32; ++i) {
      float acc = bias;
#pragma unroll
      for (int k = 0; k < 16; ++k)
        acc += dot4(w[k], *(const float4*)(s_nm + i * 64 + k * 4));
      out[OUT_EMB + (size_t)(b * 32 + i) * 1024 + e] = acc;
    }
  }
}

extern "C" void kernel_launch(void* const* d_in, const int* in_sizes, int n_in,
                              void* d_out, int out_size, void* d_ws, size_t ws_size,
                              hipStream_t stream) {
  (void)in_sizes; (void)n_in; (void)out_size; (void)ws_size;
  const float* x    = (const float*)d_in[0];
  const float* tq   = (const float*)d_in[1];
  const float* wq   = (const float*)d_in[2];
  const float* bq   = (const float*)d_in[3];
  const float* wk   = (const float*)d_in[4];
  const float* bk   = (const float*)d_in[5];
  const float* wv   = (const float*)d_in[6];
  const float* bv   = (const float*)d_in[7];
  const float* wo   = (const float*)d_in[8];
  const float* bo   = (const float*)d_in[9];
  const float* mp_w = (const float*)d_in[10];
  const float* mp_b = (const float*)d_in[11];
  const float* ln_w = (const float*)d_in[12];
  const float* ln_b = (const float*)d_in[13];
  const float* ng_w1 = (const float*)d_in[14];
  const float* ng_b1 = (const float*)d_in[15];
  const float* ng_w2 = (const float*)d_in[16];
  const float* ng_b2 = (const float*)d_in[17];
  const float* ep_w  = (const float*)d_in[20];
  const float* ep_b  = (const float*)d_in[21];
  const float* cp_w1 = (const float*)d_in[22];
  const float* cp_b1 = (const float*)d_in[23];
  const float* cp_w2 = (const float*)d_in[24];
  const float* cp_b2 = (const float*)d_in[25];
  const float* np_w  = (const float*)d_in[26];
  const float* np_b  = (const float*)d_in[27];

  float* out = (float*)d_out;
  float* ws = (float*)d_ws;
  float* qkT     = ws + OFF_QKT;
  float* qb      = ws + OFF_QB;
  float* lpart   = ws + OFF_LPART;
  float* ctx     = ws + OFF_CTX;
  float* trep    = ws + OFF_TREP;
  float* tmg     = ws + OFF_TM;
  float* nmg     = ws + OFF_NMG;
  float* partial = ws + OFF_PART;

  k_qkq<<<32, 256, 0, stream>>>(tq, wq, bq, wk, bk, qkT, qb);
  k_fused<<<512, 256, 0, stream>>>(x, qkT, qb, partial, lpart);
  k_combctx<<<128, 256, 0, stream>>>(partial, lpart, wv, bv, ctx);
  k_trep<<<1024, 256, 0, stream>>>(ctx, wo, bo, trep);
  k_tm<<<64, 256, 0, stream>>>(trep, mp_w, mp_b, tmg);
  k_nm<<<256, 256, 0, stream>>>(tmg, ln_w, ln_b, ng_w1, ng_b1, ng_w2, ng_b2, nmg);
  k_headsemb<<<80, 256, 0, stream>>>(nmg, ep_w, ep_b, cp_w1, cp_b1, cp_w2,
                                     cp_b2, np_w, np_b, out);
}

// Round 11
// 164.369 us; speedup vs baseline: 1.8780x; 1.1879x over previous
//
#include <hip/hip_runtime.h>
#include <hip/hip_bf16.h>

// ForcedDAGPlanner: B=16,S=4096,E=1024,M=64,N=32,H=8,D=128
//   scores[b,h,s] = x[b,s,:]·qk[h,:] + qb[h]   (qk = (q·Wk)/sqrt(D), 8x1024)
//   xa[b,h,:]     = softmax-weighted sum of x rows (unnormalized partials + l)
//   ctx[b,j]      = xa[b,h(j),:]·wv[j,:] + bv[j]
//   k_nodes = 32 -> node_mask all-true.
// R11: r7 structure (best, 178us) + parallelism micro-fixes:
//   k_qk 32->256 blocks (d-split, LDS reduce); k_combctx 128->256 blocks
//   (j-split, redundant xa reduce); k_tm 64->128 blocks. 8 launches.
// Law from r6/r8/r9/r10: merges/folds only win if merged work keeps
// full-chip parallelism — low-occupancy serial stages dominate everything.

#define DEVFN __device__ __forceinline__

constexpr float SCALE = 0.08838834764831845f; // 1/sqrt(128)

// workspace offsets (floats)
constexpr size_t OFF_QVEC  = 0;        // 1024
constexpr size_t OFF_QKT   = 1024;     // 8192  [h*1024+e]
constexpr size_t OFF_QB    = 9216;     // 8
constexpr size_t OFF_LPART = 9224;     // 4096  [cid*8+h]
constexpr size_t OFF_CTX   = 13320;    // 16384
constexpr size_t OFF_TREP  = 29704;    // 16384
constexpr size_t OFF_TM    = 46088;    // 1024
constexpr size_t OFF_NMG   = 47112;    // 32768
constexpr size_t OFF_PART  = 79880;    // 512*8*1024 = 4194304 [cid][h][e]
// total ~17.1 MB of d_ws

// output offsets (f32 elements)
constexpr size_t OUT_EMB  = 0;        // 16*32*1024
constexpr size_t OUT_ADJ  = 524288;   // 16*32*32
constexpr size_t OUT_SURF = 540672;   // 16
constexpr size_t OUT_CPLX = 540688;   // 16*32
constexpr size_t OUT_MASK = 541200;   // 16*32

DEVFN float gelu_exact(float x) {
  return 0.5f * x * (1.0f + erff(x * 0.70710678118654752f));
}
DEVFN float softplus_f(float x) {
  return fmaxf(x, 0.0f) + log1pf(expf(-fabsf(x)));
}
DEVFN float dot4(float4 a, float4 b) {
  return a.x * b.x + a.y * b.y + a.z * b.z + a.w * b.w;
}

// ---- K0: qvec[i] = task_query · wq[i,:] + bq[i]   (wave per output, 256 blk)
__global__ void k_qvec(const float* __restrict__ tq, const float* __restrict__ wq,
                       const float* __restrict__ bq, float* __restrict__ qvec) {
  int wid = threadIdx.x >> 6, lane = threadIdx.x & 63;
  int i = blockIdx.x * 4 + wid;
  const float* wrow = wq + (size_t)i * 1024;
  float acc = 0.f;
#pragma unroll
  for (int k = 0; k < 4; ++k) {
    int e = lane * 4 + k * 256;
    acc += dot4(*(const float4*)(tq + e), *(const float4*)(wrow + e));
  }
#pragma unroll
  for (int off = 32; off; off >>= 1) acc += __shfl_xor(acc, off);
  if (lane == 0) qvec[i] = acc + bq[i];
}

// ---- K0b v2: qkT[h*1024+e] = SCALE * qh·wk[:,e]. 256 blocks = (h, e-chunk 32).
// 8-way d-split across thread groups; LDS reduce. ~16KB wk per block.
__global__ __launch_bounds__(256) void k_qk(
    const float* __restrict__ qvec, const float* __restrict__ wk,
    const float* __restrict__ bk, float* __restrict__ qkT,
    float* __restrict__ qb) {
  __shared__ float qh[128];
  __shared__ float s_acc[8][32];
  int blk = blockIdx.x;
  int h = blk >> 5, ec = blk & 31;
  int t = threadIdx.x;
  if (t < 128) qh[t] = qvec[h * 128 + t];
  __syncthreads();
  int el = t & 31, dg = t >> 5;
  int e = ec * 32 + el;
  float acc = 0.f;
#pragma unroll
  for (int dd = 0; dd < 16; ++dd) {
    int d = dg * 16 + dd;
    acc += qh[d] * wk[(size_t)(h * 128 + d) * 1024 + e];
  }
  s_acc[dg][el] = acc;
  __syncthreads();
  if (t < 32) {
    float s = 0.f;
#pragma unroll
    for (int g = 0; g < 8; ++g) s += s_acc[g][t];
    qkT[h * 1024 + ec * 32 + t] = s * SCALE;
  }
  if (ec == 0 && t == 0) {
    float s = 0.f;
    for (int d = 0; d < 128; ++d) s += qh[d] * bk[h * 128 + d];
    qb[h] = s * SCALE;
  }
}

// ---- K1 v4 (r7 verbatim): fused score+exp+weighted-sum, single x pass.
__global__ __launch_bounds__(256, 2) void k_fused(
    const float* __restrict__ x, const float* __restrict__ qkT,
    const float* __restrict__ qb, float* __restrict__ partial,
    float* __restrict__ lpart) {
  __shared__ __align__(16) float lds[8 * 1024];
  __shared__ float s_ll[8];
  int t = threadIdx.x, wid = t >> 6, lane = t & 63;
  int rh = wid >> 1, hg = wid & 1;

  float4 qr[4][4];
#pragma unroll
  for (int hh = 0; hh < 4; ++hh)
#pragma unroll
    for (int k = 0; k < 4; ++k)
      qr[hh][k] = *(const float4*)(qkT + (hg * 4 + hh) * 1024 + k * 256 + lane * 4);
  float qbr[4];
#pragma unroll
  for (int hh = 0; hh < 4; ++hh) qbr[hh] = qb[hg * 4 + hh];

  float4 acc[4][4];
#pragma unroll
  for (int hh = 0; hh < 4; ++hh)
#pragma unroll
    for (int k = 0; k < 4; ++k) acc[hh][k] = make_float4(0.f, 0.f, 0.f, 0.f);
  float lsum[4] = {0.f, 0.f, 0.f, 0.f};

  int row0 = blockIdx.x * 128 + rh * 64;
  const float* xr = x + ((size_t)row0 << 10) + lane * 4;
  float4 A0 = *(const float4*)(xr + 0);
  float4 A1 = *(const float4*)(xr + 256);
  float4 A2 = *(const float4*)(xr + 512);
  float4 A3 = *(const float4*)(xr + 768);
  float4 B0 = *(const float4*)(xr + 1024);
  float4 B1 = *(const float4*)(xr + 1280);
  float4 B2 = *(const float4*)(xr + 1536);
  float4 B3 = *(const float4*)(xr + 1792);

  for (int r = 0; r < 64; ++r) {
    float4 c0 = A0, c1 = A1, c2 = A2, c3 = A3;
    A0 = B0; A1 = B1; A2 = B2; A3 = B3;
    if (r < 62) {
      const float* nx = xr + ((size_t)(r + 2) << 10);
      B0 = *(const float4*)(nx + 0);
      B1 = *(const float4*)(nx + 256);
      B2 = *(const float4*)(nx + 512);
      B3 = *(const float4*)(nx + 768);
    }
    float s[4];
#pragma unroll
    for (int hh = 0; hh < 4; ++hh)
      s[hh] = dot4(c0, qr[hh][0]) + dot4(c1, qr[hh][1]) +
              dot4(c2, qr[hh][2]) + dot4(c3, qr[hh][3]);
#pragma unroll
    for (int off = 1; off <= 32; off <<= 1)
#pragma unroll
      for (int hh = 0; hh < 4; ++hh) s[hh] += __shfl_xor(s[hh], off);
    float w[4];
#pragma unroll
    for (int hh = 0; hh < 4; ++hh) {
      w[hh] = expf(s[hh] + qbr[hh]);
      lsum[hh] += w[hh];
    }
#pragma unroll
    for (int hh = 0; hh < 4; ++hh) {
      acc[hh][0].x += w[hh] * c0.x; acc[hh][0].y += w[hh] * c0.y;
      acc[hh][0].z += w[hh] * c0.z; acc[hh][0].w += w[hh] * c0.w;
      acc[hh][1].x += w[hh] * c1.x; acc[hh][1].y += w[hh] * c1.y;
      acc[hh][1].z += w[hh] * c1.z; acc[hh][1].w += w[hh] * c1.w;
      acc[hh][2].x += w[hh] * c2.x; acc[hh][2].y += w[hh] * c2.y;
      acc[hh][2].z += w[hh] * c2.z; acc[hh][2].w += w[hh] * c2.w;
      acc[hh][3].x += w[hh] * c3.x; acc[hh][3].y += w[hh] * c3.y;
      acc[hh][3].z += w[hh] * c3.z; acc[hh][3].w += w[hh] * c3.w;
    }
  }
  if (rh == 1) {
#pragma unroll
    for (int hh = 0; hh < 4; ++hh)
#pragma unroll
      for (int k = 0; k < 4; ++k)
        *(float4*)(lds + (hg * 4 + hh) * 1024 + k * 256 + lane * 4) = acc[hh][k];
    if (lane == 0)
#pragma unroll
      for (int hh = 0; hh < 4; ++hh) s_ll[hg * 4 + hh] = lsum[hh];
  }
  __syncthreads();
  if (rh == 0) {
    size_t base = (((size_t)blockIdx.x * 8 + hg * 4) << 10) + lane * 4;
#pragma unroll
    for (int hh = 0; hh < 4; ++hh)
#pragma unroll
      for (int k = 0; k < 4; ++k) {
        const float4 o = *(const float4*)(lds + (hg * 4 + hh) * 1024 + k * 256 + lane * 4);
        float4 v = acc[hh][k];
        v.x += o.x; v.y += o.y; v.z += o.z; v.w += o.w;
        *(float4*)(partial + base + ((size_t)hh << 10) + k * 256) = v;
      }
    if (lane == 0)
#pragma unroll
      for (int hh = 0; hh < 4; ++hh)
        lpart[blockIdx.x * 8 + hg * 4 + hh] = lsum[hh] + s_ll[hg * 4 + hh];
  }
}

// ---- K2 v2: comb2+ctx fused, 256 blocks = (b,h,j-half). Each block reduces
// the (b,h) xa slice (duplicated across the 2 j-halves; BW-cheap) then does
// 16 wave-dots instead of 32.
__global__ __launch_bounds__(256) void k_combctx(
    const float* __restrict__ partial, const float* __restrict__ lpart,
    const float* __restrict__ wv, const float* __restrict__ bv,
    float* __restrict__ ctx) {
  __shared__ __align__(16) float s_xa[1024];
  __shared__ float s_linv;
  int blk = blockIdx.x;
  int bh = blk >> 1, jh = blk & 1;
  int b = bh >> 3, h = bh & 7, t = threadIdx.x;
  float4 s4 = make_float4(0.f, 0.f, 0.f, 0.f);
#pragma unroll 8
  for (int c = 0; c < 32; ++c) {
    float4 v = *(const float4*)(partial +
        (((size_t)(b * 32 + c) * 8 + h) << 10) + t * 4);
    s4.x += v.x; s4.y += v.y; s4.z += v.z; s4.w += v.w;
  }
  *(float4*)(s_xa + t * 4) = s4;
  if (t == 0) {
    float s = 0.f;
#pragma unroll
    for (int c = 0; c < 32; ++c) s += lpart[(b * 32 + c) * 8 + h];
    s_linv = 1.0f / s;
  }
  __syncthreads();
  int wid = t >> 6, lane = t & 63;
  float linv = s_linv;
  for (int it = 0; it < 16; ++it) {
    int j = h * 128 + jh * 64 + wid * 16 + it;
    const float* wr = wv + (size_t)j * 1024 + lane * 4;
    const float* xr = s_xa + lane * 4;
    float acc = 0.f;
#pragma unroll
    for (int k = 0; k < 4; ++k)
      acc += dot4(*(const float4*)(xr + k * 256), *(const float4*)(wr + k * 256));
#pragma unroll
    for (int off = 32; off; off >>= 1) acc += __shfl_xor(acc, off);
    if (lane == 0) ctx[b * 1024 + j] = acc * linv + bv[j];
  }
}

// ---- K3: task_repr (r7 verbatim). 1024 blocks, 16 outputs/block.
__global__ void k_trep(const float* __restrict__ ctx, const float* __restrict__ wo,
                       const float* __restrict__ bo, float* __restrict__ trep) {
  int wid = threadIdx.x >> 6, lane = threadIdx.x & 63;
#pragma unroll
  for (int it = 0; it < 4; ++it) {
    int gw = blockIdx.x * 16 + wid * 4 + it;
    int b = gw >> 10, i = gw & 1023;
    const float* xr = ctx + (size_t)b * 1024;
    const float* wr = wo + (size_t)i * 1024;
    float acc = 0.f;
#pragma unroll
    for (int k = 0; k < 4; ++k) {
      int e = lane * 4 + k * 256;
      acc += dot4(*(const float4*)(xr + e), *(const float4*)(wr + e));
    }
#pragma unroll
    for (int off = 32; off; off >>= 1) acc += __shfl_xor(acc, off);
    if (lane == 0) trep[b * 1024 + i] = acc + bo[i];
  }
}

// ---- K4 v2: tm. 128 blocks = (b, m-chunk 8); 2 outputs/wave.
__global__ void k_tm(const float* __restrict__ trep, const float* __restrict__ mp_w,
                     const float* __restrict__ mp_b, float* __restrict__ tmg) {
  int b = blockIdx.x >> 3, mc = blockIdx.x & 7;
  int wid = threadIdx.x >> 6, lane = threadIdx.x & 63;
  const float* xr = trep + (size_t)b * 1024 + lane * 4;
#pragma unroll
  for (int it = 0; it < 2; ++it) {
    int m = mc * 8 + wid * 2 + it;
    const float* wr = mp_w + (size_t)m * 1024 + lane * 4;
    float acc = 0.f;
#pragma unroll
    for (int k = 0; k < 4; ++k)
      acc += dot4(*(const float4*)(xr + k * 256), *(const float4*)(wr + k * 256));
#pragma unroll
    for (int off = 32; off; off >>= 1) acc += __shfl_xor(acc, off);
    if (lane == 0) tmg[b * 64 + m] = acc + mp_b[m];
  }
}

// ---- K5: nm (r7 verbatim). 256 blocks = (b, node-pair).
__global__ __launch_bounds__(256) void k_nm(
    const float* __restrict__ tmg, const float* __restrict__ ln_w,
    const float* __restrict__ ln_b, const float* __restrict__ ng_w1,
    const float* __restrict__ ng_b1, const float* __restrict__ ng_w2,
    const float* __restrict__ ng_b2, float* __restrict__ nmg) {
  __shared__ float s_tm[64];
  __shared__ float s_h2[128];
  __shared__ float s_np[128];
  int b = blockIdx.x >> 4, np = blockIdx.x & 15;
  int t = threadIdx.x, wid = t >> 6, lane = t & 63;
  if (wid == 0) {
    float v = tmg[b * 64 + lane];
    float sm = v;
#pragma unroll
    for (int off = 32; off; off >>= 1) sm += __shfl_xor(sm, off);
    float mu = sm * (1.f / 64.f);
    float d = v - mu;
    float vv = d * d;
#pragma unroll
    for (int off = 32; off; off >>= 1) vv += __shfl_xor(vv, off);
    float rstd = 1.f / sqrtf(vv * (1.f / 64.f) + 1e-5f);
    s_tm[lane] = d * rstd * ln_w[lane] + ln_b[lane];
  }
  __syncthreads();
  if (t < 128) {
    float acc = ng_b1[t];
    const float* wr = ng_w1 + (size_t)t * 64;
#pragma unroll 16
    for (int m = 0; m < 64; ++m) acc += s_tm[m] * wr[m];
    s_h2[t] = gelu_exact(acc);
  }
  __syncthreads();
  if (t < 128) {
    int o = np * 128 + t;
    float acc = ng_b2[o];
    const float* wr = ng_w2 + (size_t)o * 128;
#pragma unroll 8
    for (int r = 0; r < 128; ++r) acc += s_h2[r] * wr[r];
    s_np[t] = acc;
  }
  __syncthreads();
  if (wid < 2) {
    float v = s_np[wid * 64 + lane];
    float sm = v;
#pragma unroll
    for (int off = 32; off; off >>= 1) sm += __shfl_xor(sm, off);
    float mu = sm * (1.f / 64.f);
    float d = v - mu;
    float vv = d * d;
#pragma unroll
    for (int off = 32; off; off >>= 1) vv += __shfl_xor(vv, off);
    float rstd = 1.f / sqrtf(vv * (1.f / 64.f) + 1e-5f);
    nmg[b * 2048 + (np * 2 + wid) * 64 + lane] = d * rstd * ln_w[lane] + ln_b[lane];
  }
}

// ---- K6: merged heads (blocks 0..15) + node embeddings (blocks 16..79)
__global__ __launch_bounds__(256) void k_headsemb(
    const float* __restrict__ nmg, const float* __restrict__ ep_w,
    const float* __restrict__ ep_b, const float* __restrict__ cp_w1,
    const float* __restrict__ cp_b1, const float* __restrict__ cp_w2,
    const float* __restrict__ cp_b2, const float* __restrict__ np_w,
    const float* __restrict__ np_b, float* __restrict__ out) {
  __shared__ __align__(16) float s_nm[2048];
  __shared__ float s_t[2048];
  __shared__ float s_c1[1024];
  __shared__ float s_cx[32];
  int t = threadIdx.x, wid = t >> 6, lane = t & 63;
  if (blockIdx.x < 16) {
    int b = blockIdx.x;
    for (int i = t; i < 512; i += 256)
      ((float4*)s_nm)[i] = ((const float4*)(nmg + (size_t)b * 2048))[i];
    __syncthreads();
    for (int o = t; o < 1024; o += 256) {
      int i = o >> 5, r = o & 31;
      float acc = cp_b1[r];
      const float* wr = cp_w1 + (size_t)r * 64;
#pragma unroll 8
      for (int m = 0; m < 64; ++m) acc += s_nm[i * 64 + m] * wr[m];
      s_c1[o] = gelu_exact(acc);
    }
    __syncthreads();
    if (t < 32) {
      float acc = cp_b2[0];
#pragma unroll 8
      for (int r = 0; r < 32; ++r) acc += s_c1[t * 32 + r] * cp_w2[r];
      float sp = softplus_f(acc);
      s_cx[t] = sp;
      out[OUT_CPLX + b * 32 + t] = sp;
      out[OUT_MASK + b * 32 + t] = 1.0f;
    }
    __syncthreads();
    if (wid == 0) {
      float v = (lane < 32) ? s_cx[lane] : 0.f;
#pragma unroll
      for (int off = 32; off; off >>= 1) v += __shfl_xor(v, off);
      if (lane == 0) out[OUT_SURF + b] = v;
    }
    for (int o = t; o < 2048; o += 256) {
      int i = o >> 6, n = o & 63;
      float acc = 0.f;
#pragma unroll 8
      for (int m = 0; m < 64; ++m) acc += s_nm[i * 64 + m] * ep_w[m * 64 + n];
      s_t[o] = acc;
    }
    __syncthreads();
    for (int o = t; o < 1024; o += 256) {
      int i = o >> 5, j = o & 31;
      float acc = ep_b[0];
#pragma unroll 8
      for (int n = 0; n < 64; ++n) acc += s_t[i * 64 + n] * s_nm[j * 64 + n];
      float sg = 1.f / (1.f + expf(-acc));
      float val = (j > i && sg > 0.3f) ? 1.f : 0.f;
      out[OUT_ADJ + (size_t)b * 1024 + i * 32 + j] = val;
    }
  } else {
    int idx = blockIdx.x - 16;  // 64 blocks
    int b = idx >> 2, e0 = (idx & 3) * 256;
    *(float4*)(s_nm + t * 4) = *(const float4*)(nmg + b * 2048 + t * 4);
    *(float4*)(s_nm + 1024 + t * 4) =
        *(const float4*)(nmg + b * 2048 + 1024 + t * 4);
    __syncthreads();
    int e = e0 + t;
    float4 w[16];
    const float* wr = np_w + (size_t)e * 64;
#pragma unroll
    for (int k = 0; k < 16; ++k) w[k] = *(const float4*)(wr + k * 4);
    float bias = np_b[e];
    for (int i = 0; i < 32; ++i) {
      float acc = bias;
#pragma unroll
      for (int k = 0; k < 16; ++k)
        acc += dot4(w[k], *(const float4*)(s_nm + i * 64 + k * 4));
      out[OUT_EMB + (size_t)(b * 32 + i) * 1024 + e] = acc;
    }
  }
}

extern "C" void kernel_launch(void* const* d_in, const int* in_sizes, int n_in,
                              void* d_out, int out_size, void* d_ws, size_t ws_size,
                              hipStream_t stream) {
  (void)in_sizes; (void)n_in; (void)out_size; (void)ws_size;
  const float* x    = (const float*)d_in[0];
  const float* tq   = (const float*)d_in[1];
  const float* wq   = (const float*)d_in[2];
  const float* bq   = (const float*)d_in[3];
  const float* wk   = (const float*)d_in[4];
  const float* bk   = (const float*)d_in[5];
  const float* wv   = (const float*)d_in[6];
  const float* bv   = (const float*)d_in[7];
  const float* wo   = (const float*)d_in[8];
  const float* bo   = (const float*)d_in[9];
  const float* mp_w = (const float*)d_in[10];
  const float* mp_b = (const float*)d_in[11];
  const float* ln_w = (const float*)d_in[12];
  const float* ln_b = (const float*)d_in[13];
  const float* ng_w1 = (const float*)d_in[14];
  const float* ng_b1 = (const float*)d_in[15];
  const float* ng_w2 = (const float*)d_in[16];
  const float* ng_b2 = (const float*)d_in[17];
  const float* ep_w  = (const float*)d_in[20];
  const float* ep_b  = (const float*)d_in[21];
  const float* cp_w1 = (const float*)d_in[22];
  const float* cp_b1 = (const float*)d_in[23];
  const float* cp_w2 = (const float*)d_in[24];
  const float* cp_b2 = (const float*)d_in[25];
  const float* np_w  = (const float*)d_in[26];
  const float* np_b  = (const float*)d_in[27];

  float* out = (float*)d_out;
  float* ws = (float*)d_ws;
  float* qvec    = ws + OFF_QVEC;
  float* qkT     = ws + OFF_QKT;
  float* qb      = ws + OFF_QB;
  float* lpart   = ws + OFF_LPART;
  float* ctx     = ws + OFF_CTX;
  float* trep    = ws + OFF_TREP;
  float* tmg     = ws + OFF_TM;
  float* nmg     = ws + OFF_NMG;
  float* partial = ws + OFF_PART;

  k_qvec<<<256, 256, 0, stream>>>(tq, wq, bq, qvec);
  k_qk<<<256, 256, 0, stream>>>(qvec, wk, bk, qkT, qb);
  k_fused<<<512, 256, 0, stream>>>(x, qkT, qb, partial, lpart);
  k_combctx<<<256, 256, 0, stream>>>(partial, lpart, wv, bv, ctx);
  k_trep<<<1024, 256, 0, stream>>>(ctx, wo, bo, trep);
  k_tm<<<128, 256, 0, stream>>>(trep, mp_w, mp_b, tmg);
  k_nm<<<256, 256, 0, stream>>>(tmg, ln_w, ln_b, ng_w1, ng_b1, ng_w2, ng_b2, nmg);
  k_headsemb<<<80, 256, 0, stream>>>(nmg, ep_w, ep_b, cp_w1, cp_b1, cp_w2,
                                     cp_b2, np_w, np_b, out);
}